// Round 1
// baseline (88.253 us; speedup 1.0000x reference)
//
#include <hip/hip_runtime.h>

#define BB 16
#define CC 1024
#define TT 1024
#define SEG 16          // TT / 64 lanes
#define NROWS (BB * CC) // 16384
#define NTOT (NROWS * TT)

__global__ __launch_bounds__(256) void snn_fused_kernel(
    const float* __restrict__ current,
    const float* __restrict__ beta,
    const float* __restrict__ v_init,
    const float* __restrict__ v_th,
    float* __restrict__ out)
{
    const int tid  = blockIdx.x * blockDim.x + threadIdx.x;
    const int row  = tid >> 6;        // one wave64 per (b,c) row
    const int lane = threadIdx.x & 63;
    if (row >= NROWS) return;

    const int c_idx  = row & (CC - 1);
    const float bet  = beta[c_idx];

    const size_t base = (size_t)row * TT + (size_t)lane * SEG;

    // ---- load current (16 contiguous floats per lane, float4 x4) ----
    float cur[SEG];
    const float4* cp = reinterpret_cast<const float4*>(current + base);
#pragma unroll
    for (int q = 0; q < 4; ++q) {
        float4 v = cp[q];
        cur[q * 4 + 0] = v.x; cur[q * 4 + 1] = v.y;
        cur[q * 4 + 2] = v.z; cur[q * 4 + 3] = v.w;
    }
    // inject initial membrane potential at t=0
    if (lane == 0) cur[0] = fmaf(bet, v_init[row], cur[0]);

    // ---- local recurrence (unseeded) to get segment transform ----
    float m = 0.f;
#pragma unroll
    for (int j = 0; j < SEG; ++j) m = fmaf(bet, m, cur[j]);

    // segment decay a = beta^16 via squarings
    float b2 = bet * bet;
    float b4 = b2 * b2;
    float b8 = b4 * b4;
    float aa = b8 * b8;   // running 'a'
    float bb = m;         // running 'b'

    // ---- cross-lane inclusive scan of (a,b) with affine combine ----
#pragma unroll
    for (int d = 1; d < 64; d <<= 1) {
        float ap = __shfl_up(aa, d);
        float bp = __shfl_up(bb, d);
        if (lane >= d) {
            bb = fmaf(aa, bp, bb);   // b = a_cur*b_prev + b_cur
            aa = aa * ap;
        }
    }
    float carry = __shfl_up(bb, 1);  // exclusive prefix state
    if (lane == 0) carry = 0.f;

    // ---- replay recurrence seeded with carry; cur[] becomes membrane ----
    m = carry;
#pragma unroll
    for (int j = 0; j < SEG; ++j) {
        m = fmaf(bet, m, cur[j]);
        cur[j] = m;                  // membrane
    }

    // ---- spikes + local single & double cumsums ----
    int c1[SEG], c2[SEG];
    const float4* vp = reinterpret_cast<const float4*>(v_th + base);
    int s1 = 0, s2 = 0;
#pragma unroll
    for (int q = 0; q < 4; ++q) {
        float4 v = vp[q];
        float vt[4] = { v.x, v.y, v.z, v.w };
#pragma unroll
        for (int r = 0; r < 4; ++r) {
            const int j = q * 4 + r;
            const int s = (cur[j] - vt[r] > 0.f) ? 1 : 0;
            s1 += s;
            s2 += s1;
            c1[j] = s1;
            c2[j] = s2;
        }
    }

    // ---- cross-lane exclusive scan #1: spike counts -> P1 ----
    int inc = s1;
#pragma unroll
    for (int d = 1; d < 64; d <<= 1) {
        int p = __shfl_up(inc, d);
        if (lane >= d) inc += p;
    }
    int P1 = __shfl_up(inc, 1);
    if (lane == 0) P1 = 0;

    // ---- cross-lane exclusive scan #2: w = 16*P1 + Z -> PZ ----
    int inc2 = SEG * P1 + s2;
#pragma unroll
    for (int d = 1; d < 64; d <<= 1) {
        int p = __shfl_up(inc2, d);
        if (lane >= d) inc2 += p;
    }
    int PZ = __shfl_up(inc2, 1);
    if (lane == 0) PZ = 0;

    // ---- finalize z, out; vectorized stores for all three outputs ----
    float* out0 = out;                    // (z==1) ? 1 : 0
    float* out1 = out + (size_t)NTOT;     // z
    float* out2 = out + 2 * (size_t)NTOT; // membrane

    float4* o0 = reinterpret_cast<float4*>(out0 + base);
    float4* o1 = reinterpret_cast<float4*>(out1 + base);
    float4* o2 = reinterpret_cast<float4*>(out2 + base);

#pragma unroll
    for (int q = 0; q < 4; ++q) {
        float zv[4], ov[4], mv[4];
#pragma unroll
        for (int r = 0; r < 4; ++r) {
            const int j = q * 4 + r;
            const int z = PZ + (j + 1) * P1 + c2[j];
            zv[r] = (float)z;
            ov[r] = (z == 1) ? 1.0f : 0.0f;
            mv[r] = cur[j];
        }
        o0[q] = make_float4(ov[0], ov[1], ov[2], ov[3]);
        o1[q] = make_float4(zv[0], zv[1], zv[2], zv[3]);
        o2[q] = make_float4(mv[0], mv[1], mv[2], mv[3]);
    }
}

extern "C" void kernel_launch(void* const* d_in, const int* in_sizes, int n_in,
                              void* d_out, int out_size, void* d_ws, size_t ws_size,
                              hipStream_t stream) {
    const float* current = (const float*)d_in[0];
    const float* beta    = (const float*)d_in[1];
    const float* v_init  = (const float*)d_in[2];
    const float* v_th    = (const float*)d_in[3];
    float* out = (float*)d_out;

    const int threads = 256;                       // 4 waves/block
    const int waves_needed = NROWS;                // one wave per row
    const int blocks = (waves_needed * 64) / threads; // 4096
    snn_fused_kernel<<<blocks, threads, 0, stream>>>(current, beta, v_init, v_th, out);
}